// Round 1
// baseline (839.826 us; speedup 1.0000x reference)
//
#include <hip/hip_runtime.h>
#include <math.h>

// Sizes: M=2048, AVGF=16 (17 rows), HA=16 heads, DH=128, TK=4 blocks.
// ws layout (floats): ss[17*2048] altx[16*2048] qkv[3*17*2048] imv[17*2048]
//                     t[17*8192] st0[34] st1[34]

__global__ void k0_altx_init(const float* __restrict__ x,
                             const float* __restrict__ bias,
                             const float* __restrict__ cls,
                             float* __restrict__ ss,
                             float* __restrict__ altx) {
    int idx = blockIdx.x * 256 + threadIdx.x;
    if (idx < 17 * 2048) {
        int r = idx >> 11, m = idx & 2047;
        float v = bias[idx];
        if (r == 0) v += cls[m];
        ss[idx] = v;
    }
    if (idx < 16 * 2048) {
        int i = idx >> 11, m = idx & 2047;
        int c1 = m >> 6, c2 = m & 63;
        const float* p = x + (size_t)(c2 * 32 + c1) * 160 + i * 10;
        float s = 0.f;
#pragma unroll
        for (int j = 0; j < 10; ++j) s += p[j];
        altx[idx] = s * 0.1f;
    }
}

__global__ void rowstats(const float* __restrict__ ss, float* __restrict__ st) {
    int i = blockIdx.x;
    int tid = threadIdx.x;  // 256
    const float* row = ss + (size_t)i * 2048;
    float s = 0.f, q = 0.f;
    for (int j = tid; j < 2048; j += 256) {
        float v = row[j];
        s += v;
        q += v * v;
    }
#pragma unroll
    for (int off = 32; off; off >>= 1) {
        s += __shfl_xor(s, off);
        q += __shfl_xor(q, off);
    }
    __shared__ float ls[4], lq[4];
    int w = tid >> 6;
    if ((tid & 63) == 0) { ls[w] = s; lq[w] = q; }
    __syncthreads();
    if (tid == 0) {
        s = ls[0] + ls[1] + ls[2] + ls[3];
        q = lq[0] + lq[1] + lq[2] + lq[3];
        float mean = s * (1.f / 2048.f);
        float var = q * (1.f / 2048.f) - mean * mean;
        st[i * 2] = mean;
        st[i * 2 + 1] = rsqrtf(var + 1e-5f);
    }
}

// one block per head; 64 threads; thread covers d=lane and d=lane+64
__global__ void attn_kernel(const float* __restrict__ qkv, float* __restrict__ imv) {
    int h = blockIdx.x, lane = threadIdx.x;
    const float scale = 0.08838834764831845f;  // 1/sqrt(128)
    float run0 = 0.f, run1 = 0.f;
    for (int i = 0; i < 17; ++i) {
        const float* base = qkv + (size_t)i * 6144 + h * 128;
        float q0 = base[lane], q1 = base[lane + 64];
        float k0 = base[2048 + lane], k1 = base[2048 + lane + 64];
        float v0 = base[4096 + lane], v1 = base[4096 + lane + 64];
        float p = q0 * k0 + q1 * k1;
#pragma unroll
        for (int off = 32; off; off >>= 1) p += __shfl_xor(p, off);
        float rsa = p * scale;
        float iv0 = rsa * v0, iv1 = rsa * v1;
        float o0, o1;
        if (i < 16) { run0 += iv0; run1 += iv1; o0 = run0; o1 = run1; }
        else        { o0 = iv0; o1 = iv1; }
        imv[(size_t)i * 2048 + h * 128 + lane] = o0;
        imv[(size_t)i * 2048 + h * 128 + lane + 64] = o1;
    }
}

// Skinny GEMM: out[i, l] (+)= sum_m act'[i,m] * W[l,m]
// MODE 0: act' = act ; MODE 1: act' = LN(act) via stats,g,b ; MODE 2: act' = gelu(act + g)
// grid (L/256, KSPLIT); block 256; each thread owns column l = l0+tid, acc over k-chunk,
// atomicAdd to out (out must hold base values / zeros). out_bias added by chunk-0 blocks.
template <int NR, int MODE>
__global__ __launch_bounds__(256) void gemm_kernel(
    const float* __restrict__ W, const float* __restrict__ act,
    const float* __restrict__ stats, const float* __restrict__ g,
    const float* __restrict__ b, float* __restrict__ out,
    const float* __restrict__ out_bias, int L, int K, int KC) {
    __shared__ float Wl[32][257];
    __shared__ float al[NR][32];
    int tid = threadIdx.x;
    int l0 = blockIdx.x * 256;
    int k0 = blockIdx.y * KC;
    float acc[NR];
#pragma unroll
    for (int i = 0; i < NR; ++i) acc[i] = 0.f;
    int col4 = tid & 7, rb = tid >> 3;
    for (int kt = k0; kt < k0 + KC; kt += 32) {
        // stage activation tile [NR][32] with fused transform
        for (int e = tid; e < NR * 32; e += 256) {
            int i = e >> 5, ml = e & 31;
            int m = kt + ml;
            float v = act[(size_t)i * K + m];
            if (MODE == 1) v = (v - stats[i * 2]) * stats[i * 2 + 1] * g[m] + b[m];
            else if (MODE == 2) { v += g[m]; v = 0.5f * v * (1.f + erff(v * 0.70710678f)); }
            al[i][ml] = v;
        }
        // stage weight tile [256 l][32 m] transposed into LDS
#pragma unroll
        for (int it = 0; it < 8; ++it) {
            int row = it * 32 + rb;
            const float4 w4 = *reinterpret_cast<const float4*>(
                W + (size_t)(l0 + row) * K + kt + col4 * 4);
            Wl[col4 * 4 + 0][row] = w4.x;
            Wl[col4 * 4 + 1][row] = w4.y;
            Wl[col4 * 4 + 2][row] = w4.z;
            Wl[col4 * 4 + 3][row] = w4.w;
        }
        __syncthreads();
#pragma unroll
        for (int m4 = 0; m4 < 8; ++m4) {
            float w0 = Wl[m4 * 4 + 0][tid];
            float w1 = Wl[m4 * 4 + 1][tid];
            float w2 = Wl[m4 * 4 + 2][tid];
            float w3 = Wl[m4 * 4 + 3][tid];
#pragma unroll
            for (int i = 0; i < NR; ++i) {
                const float4 a = *reinterpret_cast<const float4*>(&al[i][m4 * 4]);
                acc[i] += a.x * w0 + a.y * w1 + a.z * w2 + a.w * w3;
            }
        }
        __syncthreads();
    }
    int l = l0 + tid;
#pragma unroll
    for (int i = 0; i < NR; ++i) {
        float v = acc[i];
        if (out_bias != nullptr && blockIdx.y == 0) v += out_bias[l];
        atomicAdd(&out[(size_t)i * L + l], v);
    }
}

__global__ void ln_out(const float* __restrict__ ss, const float* __restrict__ st,
                       const float* __restrict__ g, const float* __restrict__ b,
                       float* __restrict__ out) {
    int idx = blockIdx.x * 256 + threadIdx.x;
    if (idx >= 17 * 2048) return;
    int i = idx >> 11, m = idx & 2047;
    out[idx] = (ss[idx] - st[i * 2]) * st[i * 2 + 1] * g[m] + b[m];
}

extern "C" void kernel_launch(void* const* d_in, const int* in_sizes, int n_in,
                              void* d_out, int out_size, void* d_ws, size_t ws_size,
                              hipStream_t stream) {
    const float* x      = (const float*)d_in[0];
    const float* weight = (const float*)d_in[1];
    const float* bias   = (const float*)d_in[2];
    const float* cls    = (const float*)d_in[3];
    const float* Wqkv   = (const float*)d_in[4];
    const float* Wo     = (const float*)d_in[5];
    const float* ln1_g  = (const float*)d_in[6];
    const float* ln1_b  = (const float*)d_in[7];
    const float* ln2_g  = (const float*)d_in[8];
    const float* ln2_b  = (const float*)d_in[9];
    const float* ln3_g  = (const float*)d_in[10];
    const float* ln3_b  = (const float*)d_in[11];
    const float* fc1_w  = (const float*)d_in[12];
    const float* fc1_b  = (const float*)d_in[13];
    const float* fc2_w  = (const float*)d_in[14];
    const float* fc2_b  = (const float*)d_in[15];
    float* out = (float*)d_out;

    float* ws   = (float*)d_ws;
    float* ss   = ws;               // 17*2048
    float* altx = ss + 34816;       // 16*2048
    float* qkv  = altx + 32768;     // 3*17*2048 = 104448
    float* imv  = qkv + 104448;     // 17*2048
    float* tbuf = imv + 34816;      // 17*8192 = 139264
    float* st0  = tbuf + 139264;    // 34
    float* st1  = st0 + 34;         // 34

    // altx + ss-init (cls + bias)
    k0_altx_init<<<136, 256, 0, stream>>>(x, bias, cls, ss, altx);
    // ss[1:17] += altx @ weight.T   (L=2048, K=2048, 32-way k-split)
    gemm_kernel<16, 0><<<dim3(8, 32), 256, 0, stream>>>(
        weight, altx, nullptr, nullptr, nullptr, ss + 2048, nullptr, 2048, 2048, 64);
    rowstats<<<17, 256, 0, stream>>>(ss, st0);

    for (int k = 0; k < 4; ++k) {
        hipMemsetAsync(qkv, 0, (size_t)104448 * 4, stream);
        // qkv = Wqkv[k] @ ln1(ss)   (L=6144, K=2048, 16-way split)
        gemm_kernel<17, 1><<<dim3(24, 16), 256, 0, stream>>>(
            Wqkv + (size_t)k * 12582912, ss, st0, ln1_g, ln1_b, qkv, nullptr,
            6144, 2048, 128);
        attn_kernel<<<16, 64, 0, stream>>>(qkv, imv);
        // ss += imv @ Wo[k].T       (L=2048, K=2048, 32-way split)
        gemm_kernel<17, 0><<<dim3(8, 32), 256, 0, stream>>>(
            Wo + (size_t)k * 4194304, imv, nullptr, nullptr, nullptr, ss, nullptr,
            2048, 2048, 64);
        rowstats<<<17, 256, 0, stream>>>(ss, st1);
        hipMemsetAsync(tbuf, 0, (size_t)139264 * 4, stream);
        // t = fc1_w @ ln2(ss)       (L=8192, K=2048, 8-way split; raw, gelu deferred)
        gemm_kernel<17, 1><<<dim3(32, 8), 256, 0, stream>>>(
            fc1_w, ss, st1, ln2_g, ln2_b, tbuf, nullptr, 8192, 2048, 256);
        // ss += fc2_w @ gelu(t + fc1_b) + fc2_b  (L=2048, K=8192, 32-way split)
        gemm_kernel<17, 2><<<dim3(8, 32), 256, 0, stream>>>(
            fc2_w, tbuf, nullptr, fc1_b, nullptr, ss, fc2_b, 2048, 8192, 256);
        rowstats<<<17, 256, 0, stream>>>(ss, st0);
    }
    ln_out<<<136, 256, 0, stream>>>(ss, st0, ln3_g, ln3_b, out);
}